// Round 5
// baseline (645.775 us; speedup 1.0000x reference)
//
#include <hip/hip_runtime.h>
#include <hip/hip_bf16.h>
#include <hip/hip_fp16.h>

#define N_NODES 50000
#define N_EDGES 800000

typedef unsigned short ushort_t;
typedef unsigned int uint_t;
typedef __attribute__((ext_vector_type(8))) short short8;
typedef __attribute__((ext_vector_type(4))) float f32x4;

// ---------------- bf16 split helpers ----------------
__device__ inline ushort_t bf16_rne(float x) {
    uint_t u = __float_as_uint(x);
    uint_t r = (u + 0x7fffu + ((u >> 16) & 1u)) >> 16;
    return (ushort_t)r;
}
__device__ inline void split1(float x, ushort_t& h, ushort_t& l) {
    ushort_t hh = bf16_rne(x);
    float fh = __uint_as_float((uint_t)hh << 16);
    h = hh;
    l = bf16_rne(x - fh);
}

// ---------------- degree count ----------------
__global__ void count_deg_k(const int* __restrict__ src, const int* __restrict__ dst,
                            int n_edges, int* __restrict__ deg_out, int* __restrict__ deg_in) {
    int i = blockIdx.x * blockDim.x + threadIdx.x;
    if (i < n_edges) {
        atomicAdd(&deg_out[src[i]], 1);
        atomicAdd(&deg_in[dst[i]], 1);
    }
}

// ---------------- norms ----------------
__global__ void norm_k(const int* __restrict__ deg_out, const int* __restrict__ deg_in,
                       float* __restrict__ ns, float* __restrict__ nd, int n) {
    int i = blockIdx.x * blockDim.x + threadIdx.x;
    if (i < n) {
        ns[i] = 1.0f / sqrtf((float)max(deg_out[i], 1));
        nd[i] = 1.0f / sqrtf((float)max(deg_in[i], 1));
    }
}

// ---------------- exclusive scan (single block, shfl-based) ----------------
__global__ void scan_k(const int* __restrict__ deg, int* __restrict__ row_start,
                       int* __restrict__ cursor, int n) {
    __shared__ int wexcl[16];
    __shared__ int chunk_total;
    __shared__ int carry_s;
    const int tid = threadIdx.x;
    const int lane = tid & 63, wid = tid >> 6;
    if (tid == 0) carry_s = 0;
    for (int base = 0; base < n; base += 1024) {
        int i = base + tid;
        int v = (i < n) ? deg[i] : 0;
        int x = v;
#pragma unroll
        for (int off = 1; off < 64; off <<= 1) {
            int y = __shfl_up(x, off, 64);
            if (lane >= off) x += y;
        }
        __syncthreads();
        if (lane == 63) wexcl[wid] = x;
        __syncthreads();
        if (wid == 0) {
            int tv = (lane < 16) ? wexcl[lane] : 0;
            int xs = tv;
#pragma unroll
            for (int off = 1; off < 16; off <<= 1) {
                int y = __shfl_up(xs, off, 64);
                if (lane >= off) xs += y;
            }
            if (lane < 16) wexcl[lane] = xs - tv;
            if (lane == 15) chunk_total = xs;
        }
        __syncthreads();
        int carry = carry_s;
        if (i < n) {
            int o = carry + wexcl[wid] + x - v;
            row_start[i] = o;
            cursor[i] = o;
        }
        __syncthreads();
        if (tid == 0) carry_s = carry + chunk_total;
    }
    if (tid == 0) row_start[n] = carry_s;
}

// ---------------- CSR fill ----------------
__global__ void fill_csr_k(const int* __restrict__ src, const int* __restrict__ dst,
                           int n_edges, int* __restrict__ cursor, int* __restrict__ edge_src) {
    int i = blockIdx.x * blockDim.x + threadIdx.x;
    if (i < n_edges) {
        int pos = atomicAdd(&cursor[dst[i]], 1);
        edge_src[pos] = src[i];
    }
}

// ---------------- split+transpose all 4 weights in one launch ----------------
__global__ void split_weights_k(const float* __restrict__ W0, const float* __restrict__ W1,
                                const float* __restrict__ W2, const float* __restrict__ W3,
                                ushort_t* __restrict__ W0h, ushort_t* __restrict__ W0l,
                                ushort_t* __restrict__ W1h, ushort_t* __restrict__ W1l,
                                ushort_t* __restrict__ W2h, ushort_t* __restrict__ W2l,
                                ushort_t* __restrict__ W3h, ushort_t* __restrict__ W3l) {
    const int s0 = 512 * 256, s1 = s0 + 256 * 256, s2 = s1 + 256 * 128, s3 = s2 + 128 * 64;
    int idx = blockIdx.x * blockDim.x + threadIdx.x;
    const float* W;
    ushort_t *H, *L;
    int K, N, local;
    if (idx < s0) { W = W0; H = W0h; L = W0l; K = 512; N = 256; local = idx; }
    else if (idx < s1) { W = W1; H = W1h; L = W1l; K = 256; N = 256; local = idx - s0; }
    else if (idx < s2) { W = W2; H = W2h; L = W2l; K = 256; N = 128; local = idx - s1; }
    else if (idx < s3) { W = W3; H = W3h; L = W3l; K = 128; N = 64; local = idx - s2; }
    else return;
    int n = local / K;
    int k = local - n * K;
    split1(W[(size_t)k * N + n], H[local], L[local]);
}

// ---------------- MFMA GEMM: C[M,N] = fp16( ns[row] * (A @ W) ), bf16x2 3-pass ----
// BM=64, 2x2 waves, register-prefetch pipeline, padded LDS (stride 40 el = 80 B).
// ASRC=0: A as hi/lo bf16 planes [M][K]. ASRC=1: A fp32 [M][K], split inline.
// W as transposed hi/lo planes [N][K].
template <int BN, int ASRC>  // BN: 128 or 64
__global__ __launch_bounds__(256) void gemm_mfma_k(
    const float* __restrict__ Af,
    const ushort_t* __restrict__ Ahi, const ushort_t* __restrict__ Alo,
    const ushort_t* __restrict__ Bhi, const ushort_t* __restrict__ Blo,
    __half* __restrict__ C, int M, int K, int N, const float* __restrict__ ns) {
    constexpr int BM = 64, BK = 32;
    constexpr int LDA = BK + 8;     // 40 el = 80 B: 16B-aligned rows, 2-way banks only
    constexpr int TM = 2;           // 16-row tiles per wave (32 rows)
    constexpr int TN = BN / 32;     // 4 (BN=128) or 2 (BN=64)
    constexpr int NB = BN / 64;     // B staging chunks per thread
    __shared__ __attribute__((aligned(16))) ushort_t Ah[BM * LDA];
    __shared__ __attribute__((aligned(16))) ushort_t Al[BM * LDA];
    __shared__ __attribute__((aligned(16))) ushort_t Bh[BN * LDA];
    __shared__ __attribute__((aligned(16))) ushort_t Bl[BN * LDA];
    const int t = threadIdx.x;
    const int wave = t >> 6, lane = t & 63;
    const int quad = lane >> 4, l16 = lane & 15;
    const int m0 = blockIdx.x * BM, n0 = blockIdx.y * BN;
    const int wrow = (wave >> 1) * (TM * 16);
    const int wcol = (wave & 1) * (TN * 16);

    // staging coords: A = 256 chunks of 8 el (64 rows x 4 octets), 1 chunk/thread
    const int a_r = t >> 2, a_q = t & 3;
    int a_gr = m0 + a_r;
    if (a_gr >= M) a_gr = M - 1;

    f32x4 acc[TM][TN];
#pragma unroll
    for (int mi = 0; mi < TM; ++mi)
#pragma unroll
        for (int ni = 0; ni < TN; ++ni) acc[mi][ni] = (f32x4){0.f, 0.f, 0.f, 0.f};

    // prefetch registers
    float apf[8];
    short8 ahpf, alpf;
    short8 bhpf[NB], blpf[NB];

    auto loadTiles = [&](int k0) {
        if (ASRC == 1) {
            const float* ap = Af + (size_t)a_gr * K + k0 + a_q * 8;
            *(float4*)&apf[0] = *(const float4*)ap;
            *(float4*)&apf[4] = *(const float4*)(ap + 4);
        } else {
            size_t goff = (size_t)a_gr * K + k0 + a_q * 8;
            ahpf = *(const short8*)&Ahi[goff];
            alpf = *(const short8*)&Alo[goff];
        }
#pragma unroll
        for (int j = 0; j < NB; ++j) {
            int c = t + j * 256;
            int r = c >> 2, q = c & 3;
            size_t goff = (size_t)(n0 + r) * K + k0 + q * 8;
            bhpf[j] = *(const short8*)&Bhi[goff];
            blpf[j] = *(const short8*)&Blo[goff];
        }
    };
    auto storeLDS = [&]() {
        if (ASRC == 1) {
            short8 hh, ll;
#pragma unroll
            for (int ee = 0; ee < 8; ++ee) {
                ushort_t h, l;
                split1(apf[ee], h, l);
                hh[ee] = (short)h;
                ll[ee] = (short)l;
            }
            *(short8*)&Ah[a_r * LDA + a_q * 8] = hh;
            *(short8*)&Al[a_r * LDA + a_q * 8] = ll;
        } else {
            *(short8*)&Ah[a_r * LDA + a_q * 8] = ahpf;
            *(short8*)&Al[a_r * LDA + a_q * 8] = alpf;
        }
#pragma unroll
        for (int j = 0; j < NB; ++j) {
            int c = t + j * 256;
            int r = c >> 2, q = c & 3;
            *(short8*)&Bh[r * LDA + q * 8] = bhpf[j];
            *(short8*)&Bl[r * LDA + q * 8] = blpf[j];
        }
    };

    loadTiles(0);
    for (int k0 = 0; k0 < K; k0 += BK) {
        __syncthreads();  // previous iteration's MFMA fragment reads done
        storeLDS();
        __syncthreads();
        if (k0 + BK < K) loadTiles(k0 + BK);  // in flight during MFMA below
        // ---- fragments: A[m=l16][k=quad*8+j], B[k=quad*8+j][n=l16]
        short8 afh[TM], afl[TM], bfh[TN], bfl[TN];
#pragma unroll
        for (int mi = 0; mi < TM; ++mi) {
            int m = wrow + mi * 16 + l16;
            afh[mi] = *(const short8*)&Ah[m * LDA + quad * 8];
            afl[mi] = *(const short8*)&Al[m * LDA + quad * 8];
        }
#pragma unroll
        for (int ni = 0; ni < TN; ++ni) {
            int n = wcol + ni * 16 + l16;
            bfh[ni] = *(const short8*)&Bh[n * LDA + quad * 8];
            bfl[ni] = *(const short8*)&Bl[n * LDA + quad * 8];
        }
#pragma unroll
        for (int mi = 0; mi < TM; ++mi)
#pragma unroll
            for (int ni = 0; ni < TN; ++ni) {
                acc[mi][ni] = __builtin_amdgcn_mfma_f32_16x16x32_bf16(afh[mi], bfh[ni],
                                                                      acc[mi][ni], 0, 0, 0);
                acc[mi][ni] = __builtin_amdgcn_mfma_f32_16x16x32_bf16(afh[mi], bfl[ni],
                                                                      acc[mi][ni], 0, 0, 0);
                acc[mi][ni] = __builtin_amdgcn_mfma_f32_16x16x32_bf16(afl[mi], bfh[ni],
                                                                      acc[mi][ni], 0, 0, 0);
            }
    }
    // ---- epilogue: C/D layout col=l16, row=quad*4+reg; scale by ns, emit fp16
#pragma unroll
    for (int mi = 0; mi < TM; ++mi)
#pragma unroll
        for (int r = 0; r < 4; ++r) {
            int row = m0 + wrow + mi * 16 + quad * 4 + r;
            if (row < M) {
                float s = ns[row];
#pragma unroll
                for (int ni = 0; ni < TN; ++ni) {
                    C[(size_t)row * N + n0 + wcol + ni * 16 + l16] =
                        __float2half(acc[mi][ni][r] * s);
                }
            }
        }
}

// ---------------- gather-row add helper ----------------
template <int VEC>
__device__ inline void load_add(float* a, const __half* p) {
    if (VEC == 4) {
        uint2 r = *(const uint2*)p;
        __half2 h0 = *reinterpret_cast<__half2*>(&r.x);
        __half2 h1 = *reinterpret_cast<__half2*>(&r.y);
        float2 f0 = __half22float2(h0);
        float2 f1 = __half22float2(h1);
        a[0] += f0.x; a[1] += f0.y; a[2] += f1.x; a[3] += f1.y;
    } else if (VEC == 2) {
        uint_t r = *(const uint_t*)p;
        __half2 h0 = *reinterpret_cast<__half2*>(&r);
        float2 f0 = __half22float2(h0);
        a[0] += f0.x; a[1] += f0.y;
    } else {
        a[0] += __half2float(*p);
    }
}

// ---------------- CSR aggregation + fused epilogue ----------------
// res = act(nd[w] * sum_{e: dst==w} tmp[src[e]] + bias)
// OUT_MODE: 0 = fp32 only, 1 = hi/lo planes only, 2 = both
template <int VEC, int RELU, int OUT_MODE>
__global__ void agg_ep_k(const __half* __restrict__ tmp, float* __restrict__ outF,
                         ushort_t* __restrict__ outH, ushort_t* __restrict__ outL,
                         const int* __restrict__ row_start, const int* __restrict__ edge_src,
                         const float* __restrict__ nd, const float* __restrict__ bias,
                         int n_nodes, int dim) {
    int w = (blockIdx.x * blockDim.x + threadIdx.x) >> 6;
    int lane = threadIdx.x & 63;
    if (w >= n_nodes) return;
    int s = row_start[w], e = row_start[w + 1];
    int col = lane * VEC;
    float acc[4][VEC];
#pragma unroll
    for (int c = 0; c < 4; ++c)
#pragma unroll
        for (int j = 0; j < VEC; ++j) acc[c][j] = 0.f;
    int i = s;
    for (; i + 3 < e; i += 4) {
        int u0 = edge_src[i];
        int u1 = edge_src[i + 1];
        int u2 = edge_src[i + 2];
        int u3 = edge_src[i + 3];
        load_add<VEC>(acc[0], tmp + (size_t)u0 * dim + col);
        load_add<VEC>(acc[1], tmp + (size_t)u1 * dim + col);
        load_add<VEC>(acc[2], tmp + (size_t)u2 * dim + col);
        load_add<VEC>(acc[3], tmp + (size_t)u3 * dim + col);
    }
    for (; i < e; ++i) {
        int u = edge_src[i];
        load_add<VEC>(acc[0], tmp + (size_t)u * dim + col);
    }
    float d = nd[w];
    float r[VEC];
#pragma unroll
    for (int j = 0; j < VEC; ++j) {
        float v = fmaf((acc[0][j] + acc[1][j]) + (acc[2][j] + acc[3][j]), d, bias[col + j]);
        r[j] = RELU ? fmaxf(v, 0.f) : v;
    }
    size_t base = (size_t)w * dim + col;
    if (OUT_MODE != 1) {
        if (VEC == 4) {
            *(float4*)(outF + base) = make_float4(r[0], r[1], r[2], r[3]);
        } else if (VEC == 2) {
            *(float2*)(outF + base) = make_float2(r[0], r[1]);
        } else {
            outF[base] = r[0];
        }
    }
    if (OUT_MODE != 0) {
        ushort_t h[VEC], l[VEC];
#pragma unroll
        for (int j = 0; j < VEC; ++j) split1(r[j], h[j], l[j]);
        if (VEC == 4) {
            *(ushort4*)(outH + base) = make_ushort4(h[0], h[1], h[2], h[3]);
            *(ushort4*)(outL + base) = make_ushort4(l[0], l[1], l[2], l[3]);
        } else if (VEC == 2) {
            *(ushort2*)(outH + base) = make_ushort2(h[0], h[1]);
            *(ushort2*)(outL + base) = make_ushort2(l[0], l[1]);
        } else {
            outH[base] = h[0];
            outL[base] = l[0];
        }
    }
}

extern "C" void kernel_launch(void* const* d_in, const int* in_sizes, int n_in,
                              void* d_out, int out_size, void* d_ws, size_t ws_size,
                              hipStream_t stream) {
    const float* features = (const float*)d_in[0];
    const int* src = (const int*)d_in[1];
    const int* dst = (const int*)d_in[2];
    const float* W0 = (const float*)d_in[3];
    const float* b0 = (const float*)d_in[4];
    const float* W1 = (const float*)d_in[5];
    const float* b1 = (const float*)d_in[6];
    const float* W2 = (const float*)d_in[7];
    const float* b2 = (const float*)d_in[8];
    const float* W3 = (const float*)d_in[9];
    const float* b3 = (const float*)d_in[10];
    float* out = (float*)d_out;

    // workspace carve (~160 MB)
    char* p = (char*)d_ws;
    auto alloc = [&](size_t bytes) {
        void* r = (void*)p;
        p += (bytes + 255) & ~(size_t)255;
        return r;
    };
    __half* tmp = (__half*)alloc((size_t)N_NODES * 256 * 2);        // 25.6 MB GEMM out (fp16)
    ushort_t* H1hi = (ushort_t*)alloc((size_t)N_NODES * 256 * 2);   // [M][256]
    ushort_t* H1lo = (ushort_t*)alloc((size_t)N_NODES * 256 * 2);
    ushort_t* H2hi = (ushort_t*)alloc((size_t)N_NODES * 256 * 2);   // [M][256]
    ushort_t* H2lo = (ushort_t*)alloc((size_t)N_NODES * 256 * 2);
    ushort_t* H3hi = (ushort_t*)alloc((size_t)N_NODES * 128 * 2);   // [M][128]
    ushort_t* H3lo = (ushort_t*)alloc((size_t)N_NODES * 128 * 2);
    ushort_t* W0hi = (ushort_t*)alloc(512 * 256 * 2);               // Wt planes [N][K]
    ushort_t* W0lo = (ushort_t*)alloc(512 * 256 * 2);
    ushort_t* W1hi = (ushort_t*)alloc(256 * 256 * 2);
    ushort_t* W1lo = (ushort_t*)alloc(256 * 256 * 2);
    ushort_t* W2hi = (ushort_t*)alloc(256 * 128 * 2);
    ushort_t* W2lo = (ushort_t*)alloc(256 * 128 * 2);
    ushort_t* W3hi = (ushort_t*)alloc(128 * 64 * 2);
    ushort_t* W3lo = (ushort_t*)alloc(128 * 64 * 2);
    int* edge_src = (int*)alloc((size_t)N_EDGES * 4);
    int* row_start = (int*)alloc((size_t)(N_NODES + 1) * 4);
    int* cursor = (int*)alloc((size_t)N_NODES * 4);
    int* degO = (int*)alloc((size_t)N_NODES * 4);
    int* degI = (int*)alloc((size_t)N_NODES * 4);
    float* ns = (float*)alloc((size_t)N_NODES * 4);
    float* nd = (float*)alloc((size_t)N_NODES * 4);

    // ---- graph preprocessing ----
    hipMemsetAsync(degO, 0, (size_t)N_NODES * 4, stream);
    hipMemsetAsync(degI, 0, (size_t)N_NODES * 4, stream);
    count_deg_k<<<(N_EDGES + 255) / 256, 256, 0, stream>>>(src, dst, N_EDGES, degO, degI);
    norm_k<<<(N_NODES + 255) / 256, 256, 0, stream>>>(degO, degI, ns, nd, N_NODES);
    scan_k<<<1, 1024, 0, stream>>>(degI, row_start, cursor, N_NODES);
    fill_csr_k<<<(N_EDGES + 255) / 256, 256, 0, stream>>>(src, dst, N_EDGES, cursor, edge_src);

    // ---- weight splits (one launch) ----
    {
        const int tot = 512 * 256 + 256 * 256 + 256 * 128 + 128 * 64;
        split_weights_k<<<(tot + 255) / 256, 256, 0, stream>>>(
            W0, W1, W2, W3, W0hi, W0lo, W1hi, W1lo, W2hi, W2lo, W3hi, W3lo);
    }

    const int gm = (N_NODES + 63) / 64;       // 782
    const int aggBlocks = (N_NODES + 3) / 4;  // 4 waves/block

    // ---- layer 0: 512 -> 256 (feature split fused into staging) ----
    gemm_mfma_k<128, 1><<<dim3(gm, 2), 256, 0, stream>>>(features, nullptr, nullptr,
                                                         W0hi, W0lo, tmp, N_NODES, 512, 256, ns);
    agg_ep_k<4, 1, 1><<<aggBlocks, 256, 0, stream>>>(tmp, nullptr, H1hi, H1lo, row_start,
                                                     edge_src, nd, b0, N_NODES, 256);

    // ---- layer 1: 256 -> 256 ----
    gemm_mfma_k<128, 0><<<dim3(gm, 2), 256, 0, stream>>>(nullptr, H1hi, H1lo, W1hi, W1lo,
                                                         tmp, N_NODES, 256, 256, ns);
    agg_ep_k<4, 1, 1><<<aggBlocks, 256, 0, stream>>>(tmp, nullptr, H2hi, H2lo, row_start,
                                                     edge_src, nd, b1, N_NODES, 256);

    // ---- layer 2: 256 -> 128 (aspect_embed -> d_out, planes for L3) ----
    gemm_mfma_k<128, 0><<<dim3(gm, 1), 256, 0, stream>>>(nullptr, H2hi, H2lo, W2hi, W2lo,
                                                         tmp, N_NODES, 256, 128, ns);
    agg_ep_k<2, 0, 2><<<aggBlocks, 256, 0, stream>>>(tmp, out, H3hi, H3lo, row_start,
                                                     edge_src, nd, b2, N_NODES, 128);

    // ---- layer 3: 128 -> 64 (h -> d_out + 50000*128) ----
    gemm_mfma_k<64, 0><<<dim3(gm, 1), 256, 0, stream>>>(nullptr, H3hi, H3lo, W3hi, W3lo,
                                                        tmp, N_NODES, 128, 64, ns);
    agg_ep_k<1, 0, 0><<<aggBlocks, 256, 0, stream>>>(tmp, out + (size_t)N_NODES * 128,
                                                     nullptr, nullptr, row_start, edge_src,
                                                     nd, b3, N_NODES, 64);
}